// Round 10
// baseline (112.168 us; speedup 1.0000x reference)
//
#include <hip/hip_runtime.h>

// Circle loss with hard mining, fused flash-style. N=4096, D=512, 64 classes.
// ws: [0,4MB) x_bf16 normalized; [4MB,5MB) partials (4096 rows x 16 chunks x 16B);
//     [5MB,+8) {loss_sum, valid_cnt}.
// k_mainE: grid 512 = 32 rg x 16 cc, 256 thr (4 waves x 32 disjoint rows each).
// Each B-fragment ds_read feeds 2 MFMAs (halved LDS traffic/sim). B staged via
// global_load_lds DMA double-buffer (R9-proven). Single-exp online lse: pos/neg
// are mutually exclusive per sim -> one exp on the common path (rare rescale).

#define GAMMA_ 256.0f
#define MASKT_  (-1.0e4f)  // neg-side mask (m_n init 0 => exp(-1e4-0)==0)
#define MINITP_ (-1.0e4f)  // pos-side m init (m_p == exact max pos term)
#define MASKP_  (-3.0e4f)  // pos-side mask: exp(-3e4 - m_p) == 0 since m_p >= -1e4

constexpr int N_ = 4096;
constexpr int D_ = 512;
constexpr int AST_ = 520;  // LDS row stride (shorts); 1040B = 65*16B (16B-aligned rows)
constexpr int CCH_ = 16;   // col chunks (partials window fixed at 1MB => CCH=16)

typedef __bf16 bf16x8 __attribute__((ext_vector_type(8)));
typedef float  f32x4  __attribute__((ext_vector_type(4)));
typedef const unsigned int __attribute__((address_space(1)))* gp_t;
typedef unsigned int       __attribute__((address_space(3)))* lp_t;

// exact closed forms (relu folded; valid for |s| <= ~1):
__device__ __forceinline__ float pos_q(float s) {   // -g*relu(1.25-s)*(s-0.75)
    float d = s - 1.0f;
    return fmaf(d * d, 256.0f, -16.0f);
}
__device__ __forceinline__ float neg_q(float s) {   // g*relu(s+0.25)*(s-0.25)
    float q = fmaf(s * s, 256.0f, -16.0f);
    return (s >= -0.25f) ? q : 0.0f;
}
__device__ __forceinline__ void lse_merge(float m2, float S2, float& m, float& S) {
    float mm = fmaxf(m, m2);
    S = S * __expf(m - mm) + S2 * __expf(m2 - mm);
    m = mm;
}
__device__ __forceinline__ unsigned short f2bf(float f) {  // RNE
    unsigned int u = __float_as_uint(f);
    unsigned int r = u + 0x7FFFu + ((u >> 16) & 1u);
    return (unsigned short)(r >> 16);
}

// ---- kernel 1: L2 normalize rows, cast to bf16; block 0 zeroes accumulators ----
__global__ __launch_bounds__(256) void k_norm(const float* __restrict__ in,
                                              unsigned short* __restrict__ xb,
                                              float* __restrict__ acc) {
    const int row  = blockIdx.x * 4 + (threadIdx.x >> 6);
    const int lane = threadIdx.x & 63;
    const float4* src = (const float4*)(in + (size_t)row * D_) + lane * 2;
    float4 a = src[0], b = src[1];
    float ss = a.x*a.x + a.y*a.y + a.z*a.z + a.w*a.w
             + b.x*b.x + b.y*b.y + b.z*b.z + b.w*b.w;
    #pragma unroll
    for (int d = 32; d >= 1; d >>= 1) ss += __shfl_xor(ss, d);
    float rn = 1.0f / sqrtf(ss);
    float v[8] = {a.x, a.y, a.z, a.w, b.x, b.y, b.z, b.w};
    union { uint4 u; unsigned short us[8]; } pk;
    #pragma unroll
    for (int k = 0; k < 8; ++k) pk.us[k] = f2bf(v[k] * rn);
    *((uint4*)(xb + (size_t)row * D_) + lane) = pk.u;
    if (blockIdx.x == 0 && threadIdx.x < 2) acc[threadIdx.x] = 0.0f;
}

// ---- main kernel E: 512 blocks; 128 rows x 256 cols per block ----
__global__ __launch_bounds__(256, 2) void k_mainE(const unsigned short* __restrict__ xb,
                                                  const int* __restrict__ tg,
                                                  float* __restrict__ part) {
    constexpr int NST = 16;                      // 16-col stages (256 cols/block)
    __shared__ __align__(16) unsigned short Bs[2][16][AST_];

    const int tid  = threadIdx.x;
    const int wave = tid >> 6, lane = tid & 63;
    const int n16  = lane & 15, quad = lane >> 4;
    const int rg   = (int)blockIdx.x >> 4;       // row group 0..31
    const int cc   = (int)blockIdx.x & 15;       // col chunk 0..15
    const int rowBase = rg * 128 + wave * 32;    // this wave's 32 rows
    const int colBase = cc * 256;

    // A fragments for two 16-row tiles (loop-invariant, ~128 regs)
    bf16x8 af0[16], af1[16];
    {
        const bf16x8* a0p = (const bf16x8*)(xb + (size_t)(rowBase + n16) * D_ + quad * 8);
        const bf16x8* a1p = (const bf16x8*)(xb + (size_t)(rowBase + 16 + n16) * D_ + quad * 8);
        #pragma unroll
        for (int kk = 0; kk < 16; ++kk) { af0[kk] = a0p[kk * 4]; af1[kk] = a1p[kk * 4]; }
    }
    int tr[8];
    #pragma unroll
    for (int t = 0; t < 2; ++t)
        #pragma unroll
        for (int r = 0; r < 4; ++r)
            tr[t * 4 + r] = tg[rowBase + t * 16 + quad * 4 + r];

    float m_p[8], S_p[8], m_n[8], S_n[8], mxn[8];
    #pragma unroll
    for (int i = 0; i < 8; ++i) {
        m_p[i] = MINITP_; S_p[i] = 0.f; m_n[i] = 0.f; S_n[i] = 0.f; mxn[i] = -2.0f;
    }

    // per-lane global byte offset for DMA staging (col j vector = 1024 B, lane*16)
    const char* gstage = (const char*)xb + (size_t)colBase * 1024 + lane * 16;

    // issue stage 0 into buf 0: wave stages rows j = 4p+wave, lane scatters +lane*16
    #pragma unroll
    for (int p = 0; p < 4; ++p) {
        int j = p * 4 + wave;
        __builtin_amdgcn_global_load_lds((gp_t)(const void*)(gstage + j * 1024),
                                         (lp_t)(void*)&Bs[0][j][0], 16, 0, 0);
    }
    int tc_cur = tg[colBase + n16];

    #pragma unroll 1
    for (int s = 0; s < NST; ++s) {
        const int b = s & 1;
        __syncthreads();      // drains DMA for stage s (vmcnt) + all prior LDS reads

        if (s + 1 < NST) {    // one full stage of async overlap into the idle buffer
            const char* g2 = gstage + (size_t)(s + 1) * 16 * 1024;
            #pragma unroll
            for (int p = 0; p < 4; ++p) {
                int j = p * 4 + wave;
                __builtin_amdgcn_global_load_lds((gp_t)(const void*)(g2 + j * 1024),
                                                 (lp_t)(void*)&Bs[b ^ 1][j][0], 16, 0, 0);
            }
        }
        int tc_nxt = (s + 1 < NST) ? tg[colBase + (s + 1) * 16 + n16] : 0;

        f32x4 A00 = {0.f,0.f,0.f,0.f}, A01 = {0.f,0.f,0.f,0.f};
        f32x4 A10 = {0.f,0.f,0.f,0.f}, A11 = {0.f,0.f,0.f,0.f};
        #pragma unroll
        for (int kk = 0; kk < 8; ++kk) {    // each bf read feeds 2 MFMAs
            bf16x8 bf0 = *(const bf16x8*)&Bs[b][n16][(2 * kk) * 32 + quad * 8];
            bf16x8 bf1 = *(const bf16x8*)&Bs[b][n16][(2 * kk + 1) * 32 + quad * 8];
            A00 = __builtin_amdgcn_mfma_f32_16x16x32_bf16(af0[2 * kk],     bf0, A00, 0, 0, 0);
            A10 = __builtin_amdgcn_mfma_f32_16x16x32_bf16(af1[2 * kk],     bf0, A10, 0, 0, 0);
            A01 = __builtin_amdgcn_mfma_f32_16x16x32_bf16(af0[2 * kk + 1], bf1, A01, 0, 0, 0);
            A11 = __builtin_amdgcn_mfma_f32_16x16x32_bf16(af1[2 * kk + 1], bf1, A11, 0, 0, 0);
        }

        const int jcol = colBase + s * 16 + n16;
        const int rd = jcol - rowBase - quad * 4;    // tile-t diag iff rd == t*16+r
        #pragma unroll
        for (int t = 0; t < 2; ++t) {
            #pragma unroll
            for (int r = 0; r < 4; ++r) {
                const int i = t * 4 + r;
                float sim = (t == 0) ? (A00[r] + A01[r]) : (A10[r] + A11[r]);
                bool samec = (tr[i] == tc_cur);
                bool diag  = (rd == t * 16 + r);
                float d1 = sim - 1.0f;
                float tp = fmaf(d1 * d1, 256.0f, -16.0f);
                float q  = fmaf(sim * sim, 256.0f, -16.0f);
                float tn = (sim >= -0.25f) ? q : 0.0f;
                float tv = samec ? (diag ? MASKP_ : tp) : tn;   // the one live term
                float ms = samec ? m_p[i] : m_n[i];
                if (tv > ms) {                       // rare: running max moves
                    float scl = __expf(ms - tv);
                    if (samec) { S_p[i] = fmaf(S_p[i], scl, 1.0f); m_p[i] = tv; }
                    else       { S_n[i] = fmaf(S_n[i], scl, 1.0f); m_n[i] = tv; }
                } else {                             // common: single exp
                    float e = __expf(tv - ms);
                    S_p[i] += samec ? e : 0.0f;
                    S_n[i] += samec ? 0.0f : e;
                }
                mxn[i] = fmaxf(mxn[i], samec ? -2.0f : sim);
            }
        }
        tc_cur = tc_nxt;
    }

    // merge across the 16 lanes holding each row (waves own disjoint rows)
    #pragma unroll
    for (int i = 0; i < 8; ++i) {
        #pragma unroll
        for (int d = 1; d <= 8; d <<= 1) {
            lse_merge(__shfl_xor(m_p[i], d), __shfl_xor(S_p[i], d), m_p[i], S_p[i]);
            lse_merge(__shfl_xor(m_n[i], d), __shfl_xor(S_n[i], d), m_n[i], S_n[i]);
            mxn[i] = fmaxf(mxn[i], __shfl_xor(mxn[i], d));
        }
    }
    // packed partial (R8/R9-proven): pos side stores (max term, S) directly; neg
    // side stores (mxn, S) with implied m = max(0, neg_q(mxn)).
    if (n16 == 0) {
        #pragma unroll
        for (int t = 0; t < 2; ++t)
            #pragma unroll
            for (int r = 0; r < 4; ++r) {
                const int i = t * 4 + r;
                ((float4*)part)[(size_t)(rowBase + t * 16 + quad * 4 + r) * CCH_ + cc] =
                    make_float4(m_p[i], S_p[i], mxn[i], S_n[i]);
            }
    }
}

// ---- reduce: hist of tg, merge 16 chunks/row, hard-mining fix, softplus ----
__global__ __launch_bounds__(256) void k_reduceD(const float* __restrict__ part,
                                                 const int* __restrict__ tg,
                                                 float* __restrict__ acc) {
    __shared__ int hist[64];
    const int tid = threadIdx.x;
    if (tid < 64) hist[tid] = 0;
    __syncthreads();
    for (int i = tid; i < N_; i += 256) atomicAdd(&hist[tg[i]], 1);
    __syncthreads();

    const int row = blockIdx.x * 256 + tid;
    const float4* P = (const float4*)part + (size_t)row * CCH_;
    float M_p = MINITP_, Sp = 0.f, M_n = 0.f, Sn = 0.f, mxn = -2.0f;
    #pragma unroll
    for (int c = 0; c < CCH_; ++c) {
        float4 a = P[c];   // {m_p_c, Sp_c, mxn_c, Sn_c}
        lse_merge(a.x, a.y, M_p, Sp);
        float mn = (a.z > -1.5f) ? fmaxf(neg_q(a.z), 0.0f) : 0.0f;  // empty => no-op
        lse_merge(mn, a.w, M_n, Sn);
        mxn = fmaxf(mxn, a.z);
    }
    const int cnt = hist[tg[row]];
    float np2 = (float)(cnt - 1), nn2 = (float)(N_ - cnt);
    float loss = 0.f, vld = 0.f;
    if (np2 > 0.5f && nn2 > 0.5f) {
        if (np2 > 1.5f) {             // hard positive: its term (== M_p) doubles
            float t1 = M_p, t2 = 2.0f * t1;
            float mm = fmaxf(M_p, t2);
            Sp = Sp * __expf(M_p - mm) + __expf(t2 - mm) - __expf(t1 - mm);
            M_p = mm;
        }
        if (nn2 > 1.5f) {             // hard negative: term at max sim doubles
            float t1 = neg_q(mxn), t2 = 2.0f * t1;
            float mm = fmaxf(M_n, t2);
            Sn = Sn * __expf(M_n - mm) + __expf(t2 - mm) - __expf(t1 - mm);
            M_n = mm;
        }
        float z = (M_p + __logf(Sp)) + (M_n + __logf(Sn));
        loss = fmaxf(z, 0.0f) + log1pf(__expf(-fabsf(z)));   // softplus
        vld = 1.0f;
    }
    #pragma unroll
    for (int d = 32; d >= 1; d >>= 1) { loss += __shfl_xor(loss, d); vld += __shfl_xor(vld, d); }
    if ((tid & 63) == 0) { atomicAdd(&acc[0], loss); atomicAdd(&acc[1], vld); }
}

__global__ void k_final(const float* __restrict__ acc, float* __restrict__ out) {
    if (threadIdx.x == 0) out[0] = acc[0] / fmaxf(acc[1], 1.0f);
}

__global__ void k_sentinel(float* __restrict__ out) {
    if (threadIdx.x == 0) out[0] = -12345.0f;   // signals: ws too small
}

// ================= fallback path (round-4 exact, needs only 4MB+64) =================
__global__ __launch_bounds__(1024, 4) void k_main3(const unsigned short* __restrict__ xb,
                                                   const int* __restrict__ tg,
                                                   float* __restrict__ acc_g) {
    __shared__ __align__(16) unsigned short As[16 * AST_];
    __shared__ float sm[16][16][8];
    const int tid  = threadIdx.x;
    const int wave = tid >> 6, lane = tid & 63;
    const int n16  = lane & 15, quad = lane >> 4;
    const int rowBase = blockIdx.x * 16;
    {
        int row = tid >> 6, c = tid & 63;
        *(uint4*)&As[row * AST_ + c * 8] =
            *(const uint4*)(xb + (size_t)(rowBase + row) * D_ + c * 8);
    }
    int ir[4], tr[4];
    #pragma unroll
    for (int r = 0; r < 4; ++r) { ir[r] = rowBase + quad * 4 + r; tr[r] = tg[ir[r]]; }
    float m_p[4], S_p[4], m_n[4], S_n[4], mnp[4], mxn[4], sc[4];
    #pragma unroll
    for (int r = 0; r < 4; ++r) {
        m_p[r] = 0.f; S_p[r] = 0.f; m_n[r] = 0.f; S_n[r] = 0.f;
        mnp[r] = 2.0f; mxn[r] = -2.0f; sc[r] = 0.f;
    }
    __syncthreads();
    const unsigned short* Af = &As[n16 * AST_ + quad * 8];
    #pragma unroll 1
    for (int t = wave; t < N_ / 16; t += 16) {
        const int jcol = t * 16 + n16;
        const int tc = tg[jcol];
        const bf16x8* bp = (const bf16x8*)(xb + (size_t)jcol * D_ + quad * 8);
        bf16x8 bf[16];
        #pragma unroll
        for (int kk = 0; kk < 16; ++kk) bf[kk] = bp[kk * 4];
        f32x4 a0 = {0.f, 0.f, 0.f, 0.f}, a1 = {0.f, 0.f, 0.f, 0.f};
        #pragma unroll
        for (int kk = 0; kk < 8; ++kk) {
            bf16x8 af0 = *(const bf16x8*)(Af + (2 * kk) * 32);
            bf16x8 af1 = *(const bf16x8*)(Af + (2 * kk + 1) * 32);
            a0 = __builtin_amdgcn_mfma_f32_16x16x32_bf16(af0, bf[2 * kk],     a0, 0, 0, 0);
            a1 = __builtin_amdgcn_mfma_f32_16x16x32_bf16(af1, bf[2 * kk + 1], a1, 0, 0, 0);
        }
        #pragma unroll
        for (int r = 0; r < 4; ++r) {
            float s = a0[r] + a1[r];
            bool samec = (tr[r] == tc);
            bool posm  = samec && (jcol != ir[r]);
            float tp = posm  ? pos_q(s) : MASKT_;
            float tn = samec ? MASKT_ : neg_q(s);
            float mm = fmaxf(m_p[r], tp);
            S_p[r] = S_p[r] * __expf(m_p[r] - mm) + __expf(tp - mm); m_p[r] = mm;
            mm = fmaxf(m_n[r], tn);
            S_n[r] = S_n[r] * __expf(m_n[r] - mm) + __expf(tn - mm); m_n[r] = mm;
            sc[r] += samec ? 1.0f : 0.0f;
            mnp[r] = fminf(mnp[r], posm ? s : 2.0f);
            mxn[r] = fmaxf(mxn[r], samec ? -2.0f : s);
        }
    }
    #pragma unroll
    for (int r = 0; r < 4; ++r) {
        #pragma unroll
        for (int d = 1; d <= 8; d <<= 1) {
            lse_merge(__shfl_xor(m_p[r], d), __shfl_xor(S_p[r], d), m_p[r], S_p[r]);
            lse_merge(__shfl_xor(m_n[r], d), __shfl_xor(S_n[r], d), m_n[r], S_n[r]);
            mnp[r] = fminf(mnp[r], __shfl_xor(mnp[r], d));
            mxn[r] = fmaxf(mxn[r], __shfl_xor(mxn[r], d));
            sc[r] += __shfl_xor(sc[r], d);
        }
    }
    if (n16 == 0) {
        #pragma unroll
        for (int r = 0; r < 4; ++r) {
            float* q = sm[wave][quad * 4 + r];
            q[0] = m_p[r]; q[1] = S_p[r]; q[2] = m_n[r]; q[3] = S_n[r];
            q[4] = mnp[r]; q[5] = mxn[r]; q[6] = sc[r];
        }
    }
    __syncthreads();
    if (tid < 64) {
        const int L = tid & 15;
        float m_p2 = 0.f, S_p2 = 0.f, m_n2 = 0.f, S_n2 = 0.f;
        float mnp2 = 2.0f, mxn2 = -2.0f, sct = 0.f;
        #pragma unroll
        for (int w = 0; w < 16; ++w) {
            const float* q = sm[w][L];
            lse_merge(q[0], q[1], m_p2, S_p2);
            lse_merge(q[2], q[3], m_n2, S_n2);
            mnp2 = fminf(mnp2, q[4]); mxn2 = fmaxf(mxn2, q[5]);
            sct += q[6];
        }
        float loss = 0.f, vld = 0.f;
        float np2 = sct - 1.0f, nn2 = (float)N_ - sct;
        if (tid < 16 && np2 > 0.5f && nn2 > 0.5f) {
            if (np2 > 1.5f) {
                float t1 = pos_q(mnp2), t2 = 2.0f * t1;
                float mm = fmaxf(m_p2, t2);
                S_p2 = S_p2 * __expf(m_p2 - mm) + __expf(t2 - mm) - __expf(t1 - mm);
                m_p2 = mm;
            }
            if (nn2 > 1.5f) {
                float t1 = neg_q(mxn2), t2 = 2.0f * t1;
                float mm = fmaxf(m_n2, t2);
                S_n2 = S_n2 * __expf(m_n2 - mm) + __expf(t2 - mm) - __expf(t1 - mm);
                m_n2 = mm;
            }
            float z = (m_p2 + __logf(S_p2)) + (m_n2 + __logf(S_n2));
            loss = fmaxf(z, 0.0f) + log1pf(__expf(-fabsf(z)));
            vld = 1.0f;
        }
        #pragma unroll
        for (int d = 32; d >= 1; d >>= 1) {
            loss += __shfl_xor(loss, d); vld += __shfl_xor(vld, d);
        }
        if (tid == 0) { atomicAdd(&acc_g[0], loss); atomicAdd(&acc_g[1], vld); }
    }
}

extern "C" void kernel_launch(void* const* d_in, const int* in_sizes, int n_in,
                              void* d_out, int out_size, void* d_ws, size_t ws_size,
                              hipStream_t stream) {
    const float* in = (const float*)d_in[0];
    const int*   tg = (const int*)d_in[1];
    constexpr size_t MB = 1024 * 1024;
    unsigned short* xb = (unsigned short*)d_ws;

    if (ws_size >= 5 * MB + 64) {
        float* part = (float*)((char*)d_ws + 4 * MB);
        float* acc  = (float*)((char*)d_ws + 5 * MB);
        hipLaunchKernelGGL(k_norm,    dim3(N_ / 4),    dim3(256), 0, stream, in, xb, acc);
        hipLaunchKernelGGL(k_mainE,   dim3(32 * CCH_), dim3(256), 0, stream, xb, tg, part);
        hipLaunchKernelGGL(k_reduceD, dim3(N_ / 256),  dim3(256), 0, stream, part, tg, acc);
        hipLaunchKernelGGL(k_final,   dim3(1),         dim3(64),  0, stream, acc, (float*)d_out);
    } else if (ws_size >= 4 * MB + 64) {
        float* acc = (float*)((char*)d_ws + 4 * MB);
        hipLaunchKernelGGL(k_norm,  dim3(N_ / 4),  dim3(256),  0, stream, in, xb, acc);
        hipLaunchKernelGGL(k_main3, dim3(N_ / 16), dim3(1024), 0, stream, xb, tg, acc);
        hipLaunchKernelGGL(k_final, dim3(1),       dim3(64),   0, stream, acc, (float*)d_out);
    } else {
        hipLaunchKernelGGL(k_sentinel, dim3(1), dim3(64), 0, stream, (float*)d_out);
    }
}

// Round 11
// 106.409 us; speedup vs baseline: 1.0541x; 1.0541x over previous
//
#include <hip/hip_runtime.h>

// Circle loss with hard mining, fused flash-style. N=4096, D=512, 64 classes.
// ws: [0,4MB) x_bf16 normalized; [4MB,5MB) partials (4096 rows x 16 chunks x 16B);
//     [5MB,+8) {loss_sum, valid_cnt}.
// k_mainF = R9's k_mainD structure (16-row waves, grid 1024, (256,4) -> 4
// blocks/CU / 16 waves/CU, global_load_lds DMA double-buffer) + R10's
// single-exp online lse (pos/neg mutually exclusive per sim). R10's 32-row
// waves are reverted: measured -4.6 us (occupancy loss beat LDS halving).

#define GAMMA_ 256.0f
#define MASKT_  (-1.0e4f)  // neg-side mask (m_n init 0 => exp(-1e4-0)==0)
#define MINITP_ (-1.0e4f)  // pos-side m init (m_p == exact max pos term)
#define MASKP_  (-3.0e4f)  // pos-side mask: exp(-3e4 - m_p) == 0 since m_p >= -1e4

constexpr int N_ = 4096;
constexpr int D_ = 512;
constexpr int AST_ = 520;  // LDS row stride (shorts); 1040B = 65*16B (16B-aligned rows)
constexpr int CCH_ = 16;   // col chunks

typedef __bf16 bf16x8 __attribute__((ext_vector_type(8)));
typedef float  f32x4  __attribute__((ext_vector_type(4)));
typedef const unsigned int __attribute__((address_space(1)))* gp_t;
typedef unsigned int       __attribute__((address_space(3)))* lp_t;

// exact closed forms (relu folded; valid for |s| <= ~1):
__device__ __forceinline__ float pos_q(float s) {   // -g*relu(1.25-s)*(s-0.75)
    float d = s - 1.0f;
    return fmaf(d * d, 256.0f, -16.0f);
}
__device__ __forceinline__ float neg_q(float s) {   // g*relu(s+0.25)*(s-0.25)
    float q = fmaf(s * s, 256.0f, -16.0f);
    return (s >= -0.25f) ? q : 0.0f;
}
__device__ __forceinline__ void lse_merge(float m2, float S2, float& m, float& S) {
    float mm = fmaxf(m, m2);
    S = S * __expf(m - mm) + S2 * __expf(m2 - mm);
    m = mm;
}
__device__ __forceinline__ unsigned short f2bf(float f) {  // RNE
    unsigned int u = __float_as_uint(f);
    unsigned int r = u + 0x7FFFu + ((u >> 16) & 1u);
    return (unsigned short)(r >> 16);
}

// ---- kernel 1: L2 normalize rows, cast to bf16; block 0 zeroes accumulators ----
__global__ __launch_bounds__(256) void k_norm(const float* __restrict__ in,
                                              unsigned short* __restrict__ xb,
                                              float* __restrict__ acc) {
    const int row  = blockIdx.x * 4 + (threadIdx.x >> 6);
    const int lane = threadIdx.x & 63;
    const float4* src = (const float4*)(in + (size_t)row * D_) + lane * 2;
    float4 a = src[0], b = src[1];
    float ss = a.x*a.x + a.y*a.y + a.z*a.z + a.w*a.w
             + b.x*b.x + b.y*b.y + b.z*b.z + b.w*b.w;
    #pragma unroll
    for (int d = 32; d >= 1; d >>= 1) ss += __shfl_xor(ss, d);
    float rn = 1.0f / sqrtf(ss);
    float v[8] = {a.x, a.y, a.z, a.w, b.x, b.y, b.z, b.w};
    union { uint4 u; unsigned short us[8]; } pk;
    #pragma unroll
    for (int k = 0; k < 8; ++k) pk.us[k] = f2bf(v[k] * rn);
    *((uint4*)(xb + (size_t)row * D_) + lane) = pk.u;
    if (blockIdx.x == 0 && threadIdx.x < 2) acc[threadIdx.x] = 0.0f;
}

// ---- main kernel F: grid 1024 = 64 rg x 16 cc; 64 rows x 256 cols per block ----
__global__ __launch_bounds__(256, 4) void k_mainF(const unsigned short* __restrict__ xb,
                                                  const int* __restrict__ tg,
                                                  float* __restrict__ part) {
    constexpr int NST = 16;                      // 16-col stages (256 cols/block)
    __shared__ __align__(16) unsigned short Bs[2][16][AST_];

    const int tid  = threadIdx.x;
    const int wave = tid >> 6, lane = tid & 63;
    const int n16  = lane & 15, quad = lane >> 4;
    const int rg   = (int)blockIdx.x >> 4;       // row group 0..63
    const int cc   = (int)blockIdx.x & 15;       // col chunk 0..15
    const int rowBase = rg * 64 + wave * 16;     // this wave's 16 rows
    const int colBase = cc * 256;

    // A fragments: lane holds A[m=n16][k = quad*8 + kk*32 .. +8] (loop-invariant)
    bf16x8 af[16];
    {
        const bf16x8* ap = (const bf16x8*)(xb + (size_t)(rowBase + n16) * D_ + quad * 8);
        #pragma unroll
        for (int kk = 0; kk < 16; ++kk) af[kk] = ap[kk * 4];
    }
    int tr[4];
    #pragma unroll
    for (int r = 0; r < 4; ++r) tr[r] = tg[rowBase + quad * 4 + r];

    float m_p[4], S_p[4], m_n[4], S_n[4], mxn[4];
    #pragma unroll
    for (int r = 0; r < 4; ++r) {
        m_p[r] = MINITP_; S_p[r] = 0.f; m_n[r] = 0.f; S_n[r] = 0.f; mxn[r] = -2.0f;
    }

    // per-lane global byte offset for DMA staging (col j vector = 1024 B, lane*16)
    const char* gstage = (const char*)xb + (size_t)colBase * 1024 + lane * 16;

    // issue stage 0 into buf 0: wave stages rows j = 4p+wave, lane scatters +lane*16
    #pragma unroll
    for (int p = 0; p < 4; ++p) {
        int j = p * 4 + wave;
        __builtin_amdgcn_global_load_lds((gp_t)(const void*)(gstage + j * 1024),
                                         (lp_t)(void*)&Bs[0][j][0], 16, 0, 0);
    }
    int tc_cur = tg[colBase + n16];

    #pragma unroll 1
    for (int s = 0; s < NST; ++s) {
        const int b = s & 1;
        __syncthreads();      // drains DMA for stage s (vmcnt) + all prior LDS reads

        if (s + 1 < NST) {    // one full stage of async overlap into the idle buffer
            const char* g2 = gstage + (size_t)(s + 1) * 16 * 1024;
            #pragma unroll
            for (int p = 0; p < 4; ++p) {
                int j = p * 4 + wave;
                __builtin_amdgcn_global_load_lds((gp_t)(const void*)(g2 + j * 1024),
                                                 (lp_t)(void*)&Bs[b ^ 1][j][0], 16, 0, 0);
            }
        }
        int tc_nxt = (s + 1 < NST) ? tg[colBase + (s + 1) * 16 + n16] : 0;

        f32x4 a0 = {0.f, 0.f, 0.f, 0.f}, a1 = {0.f, 0.f, 0.f, 0.f};
        #pragma unroll
        for (int kk = 0; kk < 8; ++kk) {
            bf16x8 bf0 = *(const bf16x8*)&Bs[b][n16][(2 * kk) * 32 + quad * 8];
            bf16x8 bf1 = *(const bf16x8*)&Bs[b][n16][(2 * kk + 1) * 32 + quad * 8];
            a0 = __builtin_amdgcn_mfma_f32_16x16x32_bf16(af[2 * kk],     bf0, a0, 0, 0, 0);
            a1 = __builtin_amdgcn_mfma_f32_16x16x32_bf16(af[2 * kk + 1], bf1, a1, 0, 0, 0);
        }

        const int jcol = colBase + s * 16 + n16;
        const int rd = jcol - rowBase - quad * 4;    // diagonal iff rd == r
        #pragma unroll
        for (int r = 0; r < 4; ++r) {
            float sim = a0[r] + a1[r];               // sim[row r][jcol]
            bool samec = (tr[r] == tc_cur);
            bool diag  = (rd == r);
            float d1 = sim - 1.0f;
            float tp = fmaf(d1 * d1, 256.0f, -16.0f);
            float q  = fmaf(sim * sim, 256.0f, -16.0f);
            float tn = (sim >= -0.25f) ? q : 0.0f;
            float tv = samec ? (diag ? MASKP_ : tp) : tn;   // the one live term
            float ms = samec ? m_p[r] : m_n[r];
            if (tv > ms) {                           // rare: running max moves
                float scl = __expf(ms - tv);
                if (samec) { S_p[r] = fmaf(S_p[r], scl, 1.0f); m_p[r] = tv; }
                else       { S_n[r] = fmaf(S_n[r], scl, 1.0f); m_n[r] = tv; }
            } else {                                 // common: single exp
                float e = __expf(tv - ms);
                S_p[r] += samec ? e : 0.0f;
                S_n[r] += samec ? 0.0f : e;
            }
            mxn[r] = fmaxf(mxn[r], samec ? -2.0f : sim);
        }
        tc_cur = tc_nxt;
    }

    // merge across the 16 lanes holding each row (waves own disjoint rows)
    #pragma unroll
    for (int r = 0; r < 4; ++r) {
        #pragma unroll
        for (int d = 1; d <= 8; d <<= 1) {
            lse_merge(__shfl_xor(m_p[r], d), __shfl_xor(S_p[r], d), m_p[r], S_p[r]);
            lse_merge(__shfl_xor(m_n[r], d), __shfl_xor(S_n[r], d), m_n[r], S_n[r]);
            mxn[r] = fmaxf(mxn[r], __shfl_xor(mxn[r], d));
        }
    }
    // packed partial (R8/R9-proven): pos side stores (max term, S) directly; neg
    // side stores (mxn, S) with implied m = max(0, neg_q(mxn)).
    if (n16 == 0) {
        #pragma unroll
        for (int r = 0; r < 4; ++r) {
            ((float4*)part)[(size_t)(rowBase + quad * 4 + r) * CCH_ + cc] =
                make_float4(m_p[r], S_p[r], mxn[r], S_n[r]);
        }
    }
}

// ---- reduce: hist of tg, merge 16 chunks/row, hard-mining fix, softplus ----
__global__ __launch_bounds__(256) void k_reduceD(const float* __restrict__ part,
                                                 const int* __restrict__ tg,
                                                 float* __restrict__ acc) {
    __shared__ int hist[64];
    const int tid = threadIdx.x;
    if (tid < 64) hist[tid] = 0;
    __syncthreads();
    for (int i = tid; i < N_; i += 256) atomicAdd(&hist[tg[i]], 1);
    __syncthreads();

    const int row = blockIdx.x * 256 + tid;
    const float4* P = (const float4*)part + (size_t)row * CCH_;
    float M_p = MINITP_, Sp = 0.f, M_n = 0.f, Sn = 0.f, mxn = -2.0f;
    #pragma unroll
    for (int c = 0; c < CCH_; ++c) {
        float4 a = P[c];   // {m_p_c, Sp_c, mxn_c, Sn_c}
        lse_merge(a.x, a.y, M_p, Sp);
        float mn = (a.z > -1.5f) ? fmaxf(neg_q(a.z), 0.0f) : 0.0f;  // empty => no-op
        lse_merge(mn, a.w, M_n, Sn);
        mxn = fmaxf(mxn, a.z);
    }
    const int cnt = hist[tg[row]];
    float np2 = (float)(cnt - 1), nn2 = (float)(N_ - cnt);
    float loss = 0.f, vld = 0.f;
    if (np2 > 0.5f && nn2 > 0.5f) {
        if (np2 > 1.5f) {             // hard positive: its term (== M_p) doubles
            float t1 = M_p, t2 = 2.0f * t1;
            float mm = fmaxf(M_p, t2);
            Sp = Sp * __expf(M_p - mm) + __expf(t2 - mm) - __expf(t1 - mm);
            M_p = mm;
        }
        if (nn2 > 1.5f) {             // hard negative: term at max sim doubles
            float t1 = neg_q(mxn), t2 = 2.0f * t1;
            float mm = fmaxf(M_n, t2);
            Sn = Sn * __expf(M_n - mm) + __expf(t2 - mm) - __expf(t1 - mm);
            M_n = mm;
        }
        float z = (M_p + __logf(Sp)) + (M_n + __logf(Sn));
        loss = fmaxf(z, 0.0f) + log1pf(__expf(-fabsf(z)));   // softplus
        vld = 1.0f;
    }
    #pragma unroll
    for (int d = 32; d >= 1; d >>= 1) { loss += __shfl_xor(loss, d); vld += __shfl_xor(vld, d); }
    if ((tid & 63) == 0) { atomicAdd(&acc[0], loss); atomicAdd(&acc[1], vld); }
}

__global__ void k_final(const float* __restrict__ acc, float* __restrict__ out) {
    if (threadIdx.x == 0) out[0] = acc[0] / fmaxf(acc[1], 1.0f);
}

__global__ void k_sentinel(float* __restrict__ out) {
    if (threadIdx.x == 0) out[0] = -12345.0f;   // signals: ws too small
}

// ================= fallback path (round-4 exact, needs only 4MB+64) =================
__global__ __launch_bounds__(1024, 4) void k_main3(const unsigned short* __restrict__ xb,
                                                   const int* __restrict__ tg,
                                                   float* __restrict__ acc_g) {
    __shared__ __align__(16) unsigned short As[16 * AST_];
    __shared__ float sm[16][16][8];
    const int tid  = threadIdx.x;
    const int wave = tid >> 6, lane = tid & 63;
    const int n16  = lane & 15, quad = lane >> 4;
    const int rowBase = blockIdx.x * 16;
    {
        int row = tid >> 6, c = tid & 63;
        *(uint4*)&As[row * AST_ + c * 8] =
            *(const uint4*)(xb + (size_t)(rowBase + row) * D_ + c * 8);
    }
    int ir[4], tr[4];
    #pragma unroll
    for (int r = 0; r < 4; ++r) { ir[r] = rowBase + quad * 4 + r; tr[r] = tg[ir[r]]; }
    float m_p[4], S_p[4], m_n[4], S_n[4], mnp[4], mxn[4], sc[4];
    #pragma unroll
    for (int r = 0; r < 4; ++r) {
        m_p[r] = 0.f; S_p[r] = 0.f; m_n[r] = 0.f; S_n[r] = 0.f;
        mnp[r] = 2.0f; mxn[r] = -2.0f; sc[r] = 0.f;
    }
    __syncthreads();
    const unsigned short* Af = &As[n16 * AST_ + quad * 8];
    #pragma unroll 1
    for (int t = wave; t < N_ / 16; t += 16) {
        const int jcol = t * 16 + n16;
        const int tc = tg[jcol];
        const bf16x8* bp = (const bf16x8*)(xb + (size_t)jcol * D_ + quad * 8);
        bf16x8 bf[16];
        #pragma unroll
        for (int kk = 0; kk < 16; ++kk) bf[kk] = bp[kk * 4];
        f32x4 a0 = {0.f, 0.f, 0.f, 0.f}, a1 = {0.f, 0.f, 0.f, 0.f};
        #pragma unroll
        for (int kk = 0; kk < 8; ++kk) {
            bf16x8 af0 = *(const bf16x8*)(Af + (2 * kk) * 32);
            bf16x8 af1 = *(const bf16x8*)(Af + (2 * kk + 1) * 32);
            a0 = __builtin_amdgcn_mfma_f32_16x16x32_bf16(af0, bf[2 * kk],     a0, 0, 0, 0);
            a1 = __builtin_amdgcn_mfma_f32_16x16x32_bf16(af1, bf[2 * kk + 1], a1, 0, 0, 0);
        }
        #pragma unroll
        for (int r = 0; r < 4; ++r) {
            float s = a0[r] + a1[r];
            bool samec = (tr[r] == tc);
            bool posm  = samec && (jcol != ir[r]);
            float tp = posm  ? pos_q(s) : MASKT_;
            float tn = samec ? MASKT_ : neg_q(s);
            float mm = fmaxf(m_p[r], tp);
            S_p[r] = S_p[r] * __expf(m_p[r] - mm) + __expf(tp - mm); m_p[r] = mm;
            mm = fmaxf(m_n[r], tn);
            S_n[r] = S_n[r] * __expf(m_n[r] - mm) + __expf(tn - mm); m_n[r] = mm;
            sc[r] += samec ? 1.0f : 0.0f;
            mnp[r] = fminf(mnp[r], posm ? s : 2.0f);
            mxn[r] = fmaxf(mxn[r], samec ? -2.0f : s);
        }
    }
    #pragma unroll
    for (int r = 0; r < 4; ++r) {
        #pragma unroll
        for (int d = 1; d <= 8; d <<= 1) {
            lse_merge(__shfl_xor(m_p[r], d), __shfl_xor(S_p[r], d), m_p[r], S_p[r]);
            lse_merge(__shfl_xor(m_n[r], d), __shfl_xor(S_n[r], d), m_n[r], S_n[r]);
            mnp[r] = fminf(mnp[r], __shfl_xor(mnp[r], d));
            mxn[r] = fmaxf(mxn[r], __shfl_xor(mxn[r], d));
            sc[r] += __shfl_xor(sc[r], d);
        }
    }
    if (n16 == 0) {
        #pragma unroll
        for (int r = 0; r < 4; ++r) {
            float* q = sm[wave][quad * 4 + r];
            q[0] = m_p[r]; q[1] = S_p[r]; q[2] = m_n[r]; q[3] = S_n[r];
            q[4] = mnp[r]; q[5] = mxn[r]; q[6] = sc[r];
        }
    }
    __syncthreads();
    if (tid < 64) {
        const int L = tid & 15;
        float m_p2 = 0.f, S_p2 = 0.f, m_n2 = 0.f, S_n2 = 0.f;
        float mnp2 = 2.0f, mxn2 = -2.0f, sct = 0.f;
        #pragma unroll
        for (int w = 0; w < 16; ++w) {
            const float* q = sm[w][L];
            lse_merge(q[0], q[1], m_p2, S_p2);
            lse_merge(q[2], q[3], m_n2, S_n2);
            mnp2 = fminf(mnp2, q[4]); mxn2 = fmaxf(mxn2, q[5]);
            sct += q[6];
        }
        float loss = 0.f, vld = 0.f;
        float np2 = sct - 1.0f, nn2 = (float)N_ - sct;
        if (tid < 16 && np2 > 0.5f && nn2 > 0.5f) {
            if (np2 > 1.5f) {
                float t1 = pos_q(mnp2), t2 = 2.0f * t1;
                float mm = fmaxf(m_p2, t2);
                S_p2 = S_p2 * __expf(m_p2 - mm) + __expf(t2 - mm) - __expf(t1 - mm);
                m_p2 = mm;
            }
            if (nn2 > 1.5f) {
                float t1 = neg_q(mxn2), t2 = 2.0f * t1;
                float mm = fmaxf(m_n2, t2);
                S_n2 = S_n2 * __expf(m_n2 - mm) + __expf(t2 - mm) - __expf(t1 - mm);
                m_n2 = mm;
            }
            float z = (m_p2 + __logf(S_p2)) + (m_n2 + __logf(S_n2));
            loss = fmaxf(z, 0.0f) + log1pf(__expf(-fabsf(z)));
            vld = 1.0f;
        }
        #pragma unroll
        for (int d = 32; d >= 1; d >>= 1) {
            loss += __shfl_xor(loss, d); vld += __shfl_xor(vld, d);
        }
        if (tid == 0) { atomicAdd(&acc_g[0], loss); atomicAdd(&acc_g[1], vld); }
    }
}

extern "C" void kernel_launch(void* const* d_in, const int* in_sizes, int n_in,
                              void* d_out, int out_size, void* d_ws, size_t ws_size,
                              hipStream_t stream) {
    const float* in = (const float*)d_in[0];
    const int*   tg = (const int*)d_in[1];
    constexpr size_t MB = 1024 * 1024;
    unsigned short* xb = (unsigned short*)d_ws;

    if (ws_size >= 5 * MB + 64) {
        float* part = (float*)((char*)d_ws + 4 * MB);
        float* acc  = (float*)((char*)d_ws + 5 * MB);
        hipLaunchKernelGGL(k_norm,    dim3(N_ / 4),    dim3(256), 0, stream, in, xb, acc);
        hipLaunchKernelGGL(k_mainF,   dim3(64 * CCH_), dim3(256), 0, stream, xb, tg, part);
        hipLaunchKernelGGL(k_reduceD, dim3(N_ / 256),  dim3(256), 0, stream, part, tg, acc);
        hipLaunchKernelGGL(k_final,   dim3(1),         dim3(64),  0, stream, acc, (float*)d_out);
    } else if (ws_size >= 4 * MB + 64) {
        float* acc = (float*)((char*)d_ws + 4 * MB);
        hipLaunchKernelGGL(k_norm,  dim3(N_ / 4),  dim3(256),  0, stream, in, xb, acc);
        hipLaunchKernelGGL(k_main3, dim3(N_ / 16), dim3(1024), 0, stream, xb, tg, acc);
        hipLaunchKernelGGL(k_final, dim3(1),       dim3(64),   0, stream, acc, (float*)d_out);
    } else {
        hipLaunchKernelGGL(k_sentinel, dim3(1), dim3(64), 0, stream, (float*)d_out);
    }
}

// Round 12
// 105.732 us; speedup vs baseline: 1.0609x; 1.0064x over previous
//
#include <hip/hip_runtime.h>

// Circle loss with hard mining, fused flash-style. N=4096, D=512, 64 classes.
// ws: [0,4MB) x_bf16 normalized; [4MB,5MB) partials (4096 rows x 16 chunks x 16B);
//     [5MB,+16) {loss_sum, valid_cnt, ticket, pad}.
// k_mainF (unchanged, best-known 43.7us): 16-row waves, grid 1024, (256,4),
// global_load_lds DMA double-buffer, single-exp online lse.
// This round: k_final fused into k_reduceF via last-block ticket (4->3
// dispatches; ~6.6us/dispatch measured across R4/R7/R9/R11).

#define GAMMA_ 256.0f
#define MASKT_  (-1.0e4f)  // neg-side mask (m_n init 0 => exp(-1e4-0)==0)
#define MINITP_ (-1.0e4f)  // pos-side m init (m_p == exact max pos term)
#define MASKP_  (-3.0e4f)  // pos-side mask: exp(-3e4 - m_p) == 0 since m_p >= -1e4

constexpr int N_ = 4096;
constexpr int D_ = 512;
constexpr int AST_ = 520;  // LDS row stride (shorts); 1040B = 65*16B (16B-aligned rows)
constexpr int CCH_ = 16;   // col chunks

typedef __bf16 bf16x8 __attribute__((ext_vector_type(8)));
typedef float  f32x4  __attribute__((ext_vector_type(4)));
typedef const unsigned int __attribute__((address_space(1)))* gp_t;
typedef unsigned int       __attribute__((address_space(3)))* lp_t;

// exact closed forms (relu folded; valid for |s| <= ~1):
__device__ __forceinline__ float pos_q(float s) {   // -g*relu(1.25-s)*(s-0.75)
    float d = s - 1.0f;
    return fmaf(d * d, 256.0f, -16.0f);
}
__device__ __forceinline__ float neg_q(float s) {   // g*relu(s+0.25)*(s-0.25)
    float q = fmaf(s * s, 256.0f, -16.0f);
    return (s >= -0.25f) ? q : 0.0f;
}
__device__ __forceinline__ void lse_merge(float m2, float S2, float& m, float& S) {
    float mm = fmaxf(m, m2);
    S = S * __expf(m - mm) + S2 * __expf(m2 - mm);
    m = mm;
}
__device__ __forceinline__ unsigned short f2bf(float f) {  // RNE
    unsigned int u = __float_as_uint(f);
    unsigned int r = u + 0x7FFFu + ((u >> 16) & 1u);
    return (unsigned short)(r >> 16);
}

// ---- kernel 1: L2 normalize rows, cast to bf16; block 0 zeroes acc+ticket ----
__global__ __launch_bounds__(256) void k_norm(const float* __restrict__ in,
                                              unsigned short* __restrict__ xb,
                                              float* __restrict__ acc) {
    const int row  = blockIdx.x * 4 + (threadIdx.x >> 6);
    const int lane = threadIdx.x & 63;
    const float4* src = (const float4*)(in + (size_t)row * D_) + lane * 2;
    float4 a = src[0], b = src[1];
    float ss = a.x*a.x + a.y*a.y + a.z*a.z + a.w*a.w
             + b.x*b.x + b.y*b.y + b.z*b.z + b.w*b.w;
    #pragma unroll
    for (int d = 32; d >= 1; d >>= 1) ss += __shfl_xor(ss, d);
    float rn = 1.0f / sqrtf(ss);
    float v[8] = {a.x, a.y, a.z, a.w, b.x, b.y, b.z, b.w};
    union { uint4 u; unsigned short us[8]; } pk;
    #pragma unroll
    for (int k = 0; k < 8; ++k) pk.us[k] = f2bf(v[k] * rn);
    *((uint4*)(xb + (size_t)row * D_) + lane) = pk.u;
    if (blockIdx.x == 0 && threadIdx.x < 4) acc[threadIdx.x] = 0.0f;  // incl ticket
}

// ---- main kernel F (UNCHANGED from R11 best-known) ----
__global__ __launch_bounds__(256, 4) void k_mainF(const unsigned short* __restrict__ xb,
                                                  const int* __restrict__ tg,
                                                  float* __restrict__ part) {
    constexpr int NST = 16;                      // 16-col stages (256 cols/block)
    __shared__ __align__(16) unsigned short Bs[2][16][AST_];

    const int tid  = threadIdx.x;
    const int wave = tid >> 6, lane = tid & 63;
    const int n16  = lane & 15, quad = lane >> 4;
    const int rg   = (int)blockIdx.x >> 4;       // row group 0..63
    const int cc   = (int)blockIdx.x & 15;       // col chunk 0..15
    const int rowBase = rg * 64 + wave * 16;     // this wave's 16 rows
    const int colBase = cc * 256;

    // A fragments: lane holds A[m=n16][k = quad*8 + kk*32 .. +8] (loop-invariant)
    bf16x8 af[16];
    {
        const bf16x8* ap = (const bf16x8*)(xb + (size_t)(rowBase + n16) * D_ + quad * 8);
        #pragma unroll
        for (int kk = 0; kk < 16; ++kk) af[kk] = ap[kk * 4];
    }
    int tr[4];
    #pragma unroll
    for (int r = 0; r < 4; ++r) tr[r] = tg[rowBase + quad * 4 + r];

    float m_p[4], S_p[4], m_n[4], S_n[4], mxn[4];
    #pragma unroll
    for (int r = 0; r < 4; ++r) {
        m_p[r] = MINITP_; S_p[r] = 0.f; m_n[r] = 0.f; S_n[r] = 0.f; mxn[r] = -2.0f;
    }

    // per-lane global byte offset for DMA staging (col j vector = 1024 B, lane*16)
    const char* gstage = (const char*)xb + (size_t)colBase * 1024 + lane * 16;

    // issue stage 0 into buf 0: wave stages rows j = 4p+wave, lane scatters +lane*16
    #pragma unroll
    for (int p = 0; p < 4; ++p) {
        int j = p * 4 + wave;
        __builtin_amdgcn_global_load_lds((gp_t)(const void*)(gstage + j * 1024),
                                         (lp_t)(void*)&Bs[0][j][0], 16, 0, 0);
    }
    int tc_cur = tg[colBase + n16];

    #pragma unroll 1
    for (int s = 0; s < NST; ++s) {
        const int b = s & 1;
        __syncthreads();      // drains DMA for stage s (vmcnt) + all prior LDS reads

        if (s + 1 < NST) {    // one full stage of async overlap into the idle buffer
            const char* g2 = gstage + (size_t)(s + 1) * 16 * 1024;
            #pragma unroll
            for (int p = 0; p < 4; ++p) {
                int j = p * 4 + wave;
                __builtin_amdgcn_global_load_lds((gp_t)(const void*)(g2 + j * 1024),
                                                 (lp_t)(void*)&Bs[b ^ 1][j][0], 16, 0, 0);
            }
        }
        int tc_nxt = (s + 1 < NST) ? tg[colBase + (s + 1) * 16 + n16] : 0;

        f32x4 a0 = {0.f, 0.f, 0.f, 0.f}, a1 = {0.f, 0.f, 0.f, 0.f};
        #pragma unroll
        for (int kk = 0; kk < 8; ++kk) {
            bf16x8 bf0 = *(const bf16x8*)&Bs[b][n16][(2 * kk) * 32 + quad * 8];
            bf16x8 bf1 = *(const bf16x8*)&Bs[b][n16][(2 * kk + 1) * 32 + quad * 8];
            a0 = __builtin_amdgcn_mfma_f32_16x16x32_bf16(af[2 * kk],     bf0, a0, 0, 0, 0);
            a1 = __builtin_amdgcn_mfma_f32_16x16x32_bf16(af[2 * kk + 1], bf1, a1, 0, 0, 0);
        }

        const int jcol = colBase + s * 16 + n16;
        const int rd = jcol - rowBase - quad * 4;    // diagonal iff rd == r
        #pragma unroll
        for (int r = 0; r < 4; ++r) {
            float sim = a0[r] + a1[r];               // sim[row r][jcol]
            bool samec = (tr[r] == tc_cur);
            bool diag  = (rd == r);
            float d1 = sim - 1.0f;
            float tp = fmaf(d1 * d1, 256.0f, -16.0f);
            float q  = fmaf(sim * sim, 256.0f, -16.0f);
            float tn = (sim >= -0.25f) ? q : 0.0f;
            float tv = samec ? (diag ? MASKP_ : tp) : tn;   // the one live term
            float ms = samec ? m_p[r] : m_n[r];
            if (tv > ms) {                           // rare: running max moves
                float scl = __expf(ms - tv);
                if (samec) { S_p[r] = fmaf(S_p[r], scl, 1.0f); m_p[r] = tv; }
                else       { S_n[r] = fmaf(S_n[r], scl, 1.0f); m_n[r] = tv; }
            } else {                                 // common: single exp
                float e = __expf(tv - ms);
                S_p[r] += samec ? e : 0.0f;
                S_n[r] += samec ? 0.0f : e;
            }
            mxn[r] = fmaxf(mxn[r], samec ? -2.0f : sim);
        }
        tc_cur = tc_nxt;
    }

    // merge across the 16 lanes holding each row (waves own disjoint rows)
    #pragma unroll
    for (int r = 0; r < 4; ++r) {
        #pragma unroll
        for (int d = 1; d <= 8; d <<= 1) {
            lse_merge(__shfl_xor(m_p[r], d), __shfl_xor(S_p[r], d), m_p[r], S_p[r]);
            lse_merge(__shfl_xor(m_n[r], d), __shfl_xor(S_n[r], d), m_n[r], S_n[r]);
            mxn[r] = fmaxf(mxn[r], __shfl_xor(mxn[r], d));
        }
    }
    // packed partial (R8/R9-proven): pos side stores (max term, S) directly; neg
    // side stores (mxn, S) with implied m = max(0, neg_q(mxn)).
    if (n16 == 0) {
        #pragma unroll
        for (int r = 0; r < 4; ++r) {
            ((float4*)part)[(size_t)(rowBase + quad * 4 + r) * CCH_ + cc] =
                make_float4(m_p[r], S_p[r], mxn[r], S_n[r]);
        }
    }
}

// ---- reduce+final fused: hist, merge 16 chunks/row, hard-mining fix, softplus,
// ---- block atomics, then last-block ticket writes out = loss/valid ----
__global__ __launch_bounds__(256) void k_reduceF(const float* __restrict__ part,
                                                 const int* __restrict__ tg,
                                                 float* __restrict__ acc,
                                                 float* __restrict__ out) {
    __shared__ int hist[64];
    const int tid = threadIdx.x;
    if (tid < 64) hist[tid] = 0;
    __syncthreads();
    for (int i = tid; i < N_; i += 256) atomicAdd(&hist[tg[i]], 1);
    __syncthreads();

    const int row = blockIdx.x * 256 + tid;
    const float4* P = (const float4*)part + (size_t)row * CCH_;
    float M_p = MINITP_, Sp = 0.f, M_n = 0.f, Sn = 0.f, mxn = -2.0f;
    #pragma unroll
    for (int c = 0; c < CCH_; ++c) {
        float4 a = P[c];   // {m_p_c, Sp_c, mxn_c, Sn_c}
        lse_merge(a.x, a.y, M_p, Sp);
        float mn = (a.z > -1.5f) ? fmaxf(neg_q(a.z), 0.0f) : 0.0f;  // empty => no-op
        lse_merge(mn, a.w, M_n, Sn);
        mxn = fmaxf(mxn, a.z);
    }
    const int cnt = hist[tg[row]];
    float np2 = (float)(cnt - 1), nn2 = (float)(N_ - cnt);
    float loss = 0.f, vld = 0.f;
    if (np2 > 0.5f && nn2 > 0.5f) {
        if (np2 > 1.5f) {             // hard positive: its term (== M_p) doubles
            float t1 = M_p, t2 = 2.0f * t1;
            float mm = fmaxf(M_p, t2);
            Sp = Sp * __expf(M_p - mm) + __expf(t2 - mm) - __expf(t1 - mm);
            M_p = mm;
        }
        if (nn2 > 1.5f) {             // hard negative: term at max sim doubles
            float t1 = neg_q(mxn), t2 = 2.0f * t1;
            float mm = fmaxf(M_n, t2);
            Sn = Sn * __expf(M_n - mm) + __expf(t2 - mm) - __expf(t1 - mm);
            M_n = mm;
        }
        float z = (M_p + __logf(Sp)) + (M_n + __logf(Sn));
        loss = fmaxf(z, 0.0f) + log1pf(__expf(-fabsf(z)));   // softplus
        vld = 1.0f;
    }
    #pragma unroll
    for (int d = 32; d >= 1; d >>= 1) { loss += __shfl_xor(loss, d); vld += __shfl_xor(vld, d); }
    if ((tid & 63) == 0) { atomicAdd(&acc[0], loss); atomicAdd(&acc[1], vld); }

    __syncthreads();                  // this block's atomics are issued
    if (tid == 0) {
        __threadfence();              // device-scope: adds visible before ticket
        int old = atomicAdd((int*)(acc + 2), 1);            // acc[2] zeroed by k_norm
        if (old == (int)gridDim.x - 1) {                    // last block finalizes
            float ls = atomicAdd(&acc[0], 0.0f);            // device-scope reads
            float lv = atomicAdd(&acc[1], 0.0f);
            out[0] = ls / fmaxf(lv, 1.0f);
        }
    }
}

__global__ void k_final(const float* __restrict__ acc, float* __restrict__ out) {
    if (threadIdx.x == 0) out[0] = acc[0] / fmaxf(acc[1], 1.0f);
}

__global__ void k_sentinel(float* __restrict__ out) {
    if (threadIdx.x == 0) out[0] = -12345.0f;   // signals: ws too small
}

// ================= fallback path (round-4 exact, needs only 4MB+64) =================
__global__ __launch_bounds__(1024, 4) void k_main3(const unsigned short* __restrict__ xb,
                                                   const int* __restrict__ tg,
                                                   float* __restrict__ acc_g) {
    __shared__ __align__(16) unsigned short As[16 * AST_];
    __shared__ float sm[16][16][8];
    const int tid  = threadIdx.x;
    const int wave = tid >> 6, lane = tid & 63;
    const int n16  = lane & 15, quad = lane >> 4;
    const int rowBase = blockIdx.x * 16;
    {
        int row = tid >> 6, c = tid & 63;
        *(uint4*)&As[row * AST_ + c * 8] =
            *(const uint4*)(xb + (size_t)(rowBase + row) * D_ + c * 8);
    }
    int ir[4], tr[4];
    #pragma unroll
    for (int r = 0; r < 4; ++r) { ir[r] = rowBase + quad * 4 + r; tr[r] = tg[ir[r]]; }
    float m_p[4], S_p[4], m_n[4], S_n[4], mnp[4], mxn[4], sc[4];
    #pragma unroll
    for (int r = 0; r < 4; ++r) {
        m_p[r] = 0.f; S_p[r] = 0.f; m_n[r] = 0.f; S_n[r] = 0.f;
        mnp[r] = 2.0f; mxn[r] = -2.0f; sc[r] = 0.f;
    }
    __syncthreads();
    const unsigned short* Af = &As[n16 * AST_ + quad * 8];
    #pragma unroll 1
    for (int t = wave; t < N_ / 16; t += 16) {
        const int jcol = t * 16 + n16;
        const int tc = tg[jcol];
        const bf16x8* bp = (const bf16x8*)(xb + (size_t)jcol * D_ + quad * 8);
        bf16x8 bf[16];
        #pragma unroll
        for (int kk = 0; kk < 16; ++kk) bf[kk] = bp[kk * 4];
        f32x4 a0 = {0.f, 0.f, 0.f, 0.f}, a1 = {0.f, 0.f, 0.f, 0.f};
        #pragma unroll
        for (int kk = 0; kk < 8; ++kk) {
            bf16x8 af0 = *(const bf16x8*)(Af + (2 * kk) * 32);
            bf16x8 af1 = *(const bf16x8*)(Af + (2 * kk + 1) * 32);
            a0 = __builtin_amdgcn_mfma_f32_16x16x32_bf16(af0, bf[2 * kk],     a0, 0, 0, 0);
            a1 = __builtin_amdgcn_mfma_f32_16x16x32_bf16(af1, bf[2 * kk + 1], a1, 0, 0, 0);
        }
        #pragma unroll
        for (int r = 0; r < 4; ++r) {
            float s = a0[r] + a1[r];
            bool samec = (tr[r] == tc);
            bool posm  = samec && (jcol != ir[r]);
            float tp = posm  ? pos_q(s) : MASKT_;
            float tn = samec ? MASKT_ : neg_q(s);
            float mm = fmaxf(m_p[r], tp);
            S_p[r] = S_p[r] * __expf(m_p[r] - mm) + __expf(tp - mm); m_p[r] = mm;
            mm = fmaxf(m_n[r], tn);
            S_n[r] = S_n[r] * __expf(m_n[r] - mm) + __expf(tn - mm); m_n[r] = mm;
            sc[r] += samec ? 1.0f : 0.0f;
            mnp[r] = fminf(mnp[r], posm ? s : 2.0f);
            mxn[r] = fmaxf(mxn[r], samec ? -2.0f : s);
        }
    }
    #pragma unroll
    for (int r = 0; r < 4; ++r) {
        #pragma unroll
        for (int d = 1; d <= 8; d <<= 1) {
            lse_merge(__shfl_xor(m_p[r], d), __shfl_xor(S_p[r], d), m_p[r], S_p[r]);
            lse_merge(__shfl_xor(m_n[r], d), __shfl_xor(S_n[r], d), m_n[r], S_n[r]);
            mnp[r] = fminf(mnp[r], __shfl_xor(mnp[r], d));
            mxn[r] = fmaxf(mxn[r], __shfl_xor(mxn[r], d));
            sc[r] += __shfl_xor(sc[r], d);
        }
    }
    if (n16 == 0) {
        #pragma unroll
        for (int r = 0; r < 4; ++r) {
            float* q = sm[wave][quad * 4 + r];
            q[0] = m_p[r]; q[1] = S_p[r]; q[2] = m_n[r]; q[3] = S_n[r];
            q[4] = mnp[r]; q[5] = mxn[r]; q[6] = sc[r];
        }
    }
    __syncthreads();
    if (tid < 64) {
        const int L = tid & 15;
        float m_p2 = 0.f, S_p2 = 0.f, m_n2 = 0.f, S_n2 = 0.f;
        float mnp2 = 2.0f, mxn2 = -2.0f, sct = 0.f;
        #pragma unroll
        for (int w = 0; w < 16; ++w) {
            const float* q = sm[w][L];
            lse_merge(q[0], q[1], m_p2, S_p2);
            lse_merge(q[2], q[3], m_n2, S_n2);
            mnp2 = fminf(mnp2, q[4]); mxn2 = fmaxf(mxn2, q[5]);
            sct += q[6];
        }
        float loss = 0.f, vld = 0.f;
        float np2 = sct - 1.0f, nn2 = (float)N_ - sct;
        if (tid < 16 && np2 > 0.5f && nn2 > 0.5f) {
            if (np2 > 1.5f) {
                float t1 = pos_q(mnp2), t2 = 2.0f * t1;
                float mm = fmaxf(m_p2, t2);
                S_p2 = S_p2 * __expf(m_p2 - mm) + __expf(t2 - mm) - __expf(t1 - mm);
                m_p2 = mm;
            }
            if (nn2 > 1.5f) {
                float t1 = neg_q(mxn2), t2 = 2.0f * t1;
                float mm = fmaxf(m_n2, t2);
                S_n2 = S_n2 * __expf(m_n2 - mm) + __expf(t2 - mm) - __expf(t1 - mm);
                m_n2 = mm;
            }
            float z = (m_p2 + __logf(S_p2)) + (m_n2 + __logf(S_n2));
            loss = fmaxf(z, 0.0f) + log1pf(__expf(-fabsf(z)));
            vld = 1.0f;
        }
        #pragma unroll
        for (int d = 32; d >= 1; d >>= 1) {
            loss += __shfl_xor(loss, d); vld += __shfl_xor(vld, d);
        }
        if (tid == 0) { atomicAdd(&acc_g[0], loss); atomicAdd(&acc_g[1], vld); }
    }
}

extern "C" void kernel_launch(void* const* d_in, const int* in_sizes, int n_in,
                              void* d_out, int out_size, void* d_ws, size_t ws_size,
                              hipStream_t stream) {
    const float* in = (const float*)d_in[0];
    const int*   tg = (const int*)d_in[1];
    constexpr size_t MB = 1024 * 1024;
    unsigned short* xb = (unsigned short*)d_ws;

    if (ws_size >= 5 * MB + 64) {
        float* part = (float*)((char*)d_ws + 4 * MB);
        float* acc  = (float*)((char*)d_ws + 5 * MB);
        hipLaunchKernelGGL(k_norm,    dim3(N_ / 4),    dim3(256), 0, stream, in, xb, acc);
        hipLaunchKernelGGL(k_mainF,   dim3(64 * CCH_), dim3(256), 0, stream, xb, tg, part);
        hipLaunchKernelGGL(k_reduceF, dim3(N_ / 256),  dim3(256), 0, stream, part, tg, acc,
                           (float*)d_out);
    } else if (ws_size >= 4 * MB + 64) {
        float* acc = (float*)((char*)d_ws + 4 * MB);
        hipLaunchKernelGGL(k_norm,  dim3(N_ / 4),  dim3(256),  0, stream, in, xb, acc);
        hipLaunchKernelGGL(k_main3, dim3(N_ / 16), dim3(1024), 0, stream, xb, tg, acc);
        hipLaunchKernelGGL(k_final, dim3(1),       dim3(64),   0, stream, acc, (float*)d_out);
    } else {
        hipLaunchKernelGGL(k_sentinel, dim3(1), dim3(64), 0, stream, (float*)d_out);
    }
}

// Round 13
// 104.942 us; speedup vs baseline: 1.0688x; 1.0075x over previous
//
#include <hip/hip_runtime.h>

// Circle loss with hard mining, fused flash-style. N=4096, D=512, 64 classes.
// ws: [0,4MB) x_bf16 normalized; [4MB,5MB) partials (4096 rows x 16 chunks x 16B);
//     [5MB,+16) {loss_sum, valid_cnt, ticket, pad}.
// k_mainG = k_mainF (16-row waves, grid 1024, (256,4), global_load_lds DMA
// double-buffer, single-exp online lse) + micro-optimized epilogue:
//   - shared quadratic: u = samec ? s-1 : s; t = 256u^2-16 covers both terms
//   - diagonal handling hoisted to the single wave-uniform stage (j0==rowBase)
//   - neg clamp folded branchlessly

#define GAMMA_ 256.0f
#define MASKT_  (-1.0e4f)  // neg-side mask (m_n init 0 => exp(-1e4-0)==0)
#define MINITP_ (-1.0e4f)  // pos-side m init (m_p == exact max pos term)
#define MASKP_  (-3.0e4f)  // pos-side mask: exp(-3e4 - m_p) == 0 since m_p >= -1e4

constexpr int N_ = 4096;
constexpr int D_ = 512;
constexpr int AST_ = 520;  // LDS row stride (shorts); 1040B = 65*16B (16B-aligned rows)
constexpr int CCH_ = 16;   // col chunks

typedef __bf16 bf16x8 __attribute__((ext_vector_type(8)));
typedef float  f32x4  __attribute__((ext_vector_type(4)));
typedef const unsigned int __attribute__((address_space(1)))* gp_t;
typedef unsigned int       __attribute__((address_space(3)))* lp_t;

// exact closed forms (relu folded; valid for |s| <= ~1):
__device__ __forceinline__ float pos_q(float s) {   // -g*relu(1.25-s)*(s-0.75)
    float d = s - 1.0f;
    return fmaf(d * d, 256.0f, -16.0f);
}
__device__ __forceinline__ float neg_q(float s) {   // g*relu(s+0.25)*(s-0.25)
    float q = fmaf(s * s, 256.0f, -16.0f);
    return (s >= -0.25f) ? q : 0.0f;
}
__device__ __forceinline__ void lse_merge(float m2, float S2, float& m, float& S) {
    float mm = fmaxf(m, m2);
    S = S * __expf(m - mm) + S2 * __expf(m2 - mm);
    m = mm;
}
__device__ __forceinline__ unsigned short f2bf(float f) {  // RNE
    unsigned int u = __float_as_uint(f);
    unsigned int r = u + 0x7FFFu + ((u >> 16) & 1u);
    return (unsigned short)(r >> 16);
}

// ---- kernel 1: L2 normalize rows, cast to bf16; block 0 zeroes acc+ticket ----
__global__ __launch_bounds__(256) void k_norm(const float* __restrict__ in,
                                              unsigned short* __restrict__ xb,
                                              float* __restrict__ acc) {
    const int row  = blockIdx.x * 4 + (threadIdx.x >> 6);
    const int lane = threadIdx.x & 63;
    const float4* src = (const float4*)(in + (size_t)row * D_) + lane * 2;
    float4 a = src[0], b = src[1];
    float ss = a.x*a.x + a.y*a.y + a.z*a.z + a.w*a.w
             + b.x*b.x + b.y*b.y + b.z*b.z + b.w*b.w;
    #pragma unroll
    for (int d = 32; d >= 1; d >>= 1) ss += __shfl_xor(ss, d);
    float rn = 1.0f / sqrtf(ss);
    float v[8] = {a.x, a.y, a.z, a.w, b.x, b.y, b.z, b.w};
    union { uint4 u; unsigned short us[8]; } pk;
    #pragma unroll
    for (int k = 0; k < 8; ++k) pk.us[k] = f2bf(v[k] * rn);
    *((uint4*)(xb + (size_t)row * D_) + lane) = pk.u;
    if (blockIdx.x == 0 && threadIdx.x < 4) acc[threadIdx.x] = 0.0f;  // incl ticket
}

// ---- main kernel G ----
__global__ __launch_bounds__(256, 4) void k_mainG(const unsigned short* __restrict__ xb,
                                                  const int* __restrict__ tg,
                                                  float* __restrict__ part) {
    constexpr int NST = 16;                      // 16-col stages (256 cols/block)
    __shared__ __align__(16) unsigned short Bs[2][16][AST_];

    const int tid  = threadIdx.x;
    const int wave = tid >> 6, lane = tid & 63;
    const int n16  = lane & 15, quad = lane >> 4;
    const int rg   = (int)blockIdx.x >> 4;       // row group 0..63
    const int cc   = (int)blockIdx.x & 15;       // col chunk 0..15
    const int rowBase = rg * 64 + wave * 16;     // this wave's 16 rows
    const int colBase = cc * 256;

    // A fragments: lane holds A[m=n16][k = quad*8 + kk*32 .. +8] (loop-invariant)
    bf16x8 af[16];
    {
        const bf16x8* ap = (const bf16x8*)(xb + (size_t)(rowBase + n16) * D_ + quad * 8);
        #pragma unroll
        for (int kk = 0; kk < 16; ++kk) af[kk] = ap[kk * 4];
    }
    int tr[4];
    #pragma unroll
    for (int r = 0; r < 4; ++r) tr[r] = tg[rowBase + quad * 4 + r];

    float m_p[4], S_p[4], m_n[4], S_n[4], mxn[4];
    #pragma unroll
    for (int r = 0; r < 4; ++r) {
        m_p[r] = MINITP_; S_p[r] = 0.f; m_n[r] = 0.f; S_n[r] = 0.f; mxn[r] = -2.0f;
    }

    // per-lane global byte offset for DMA staging (col j vector = 1024 B, lane*16)
    const char* gstage = (const char*)xb + (size_t)colBase * 1024 + lane * 16;

    // issue stage 0 into buf 0: wave stages rows j = 4p+wave, lane scatters +lane*16
    #pragma unroll
    for (int p = 0; p < 4; ++p) {
        int j = p * 4 + wave;
        __builtin_amdgcn_global_load_lds((gp_t)(const void*)(gstage + j * 1024),
                                         (lp_t)(void*)&Bs[0][j][0], 16, 0, 0);
    }
    int tc_cur = tg[colBase + n16];

    // epilogue for one stage; withDiag folded at compile time via literal call
    auto epi = [&](const f32x4& a0, const f32x4& a1, int tcv, bool withDiag) {
        #pragma unroll
        for (int r = 0; r < 4; ++r) {
            float sim = a0[r] + a1[r];               // sim[row r][jcol]
            bool samec = (tr[r] == tcv);
            float u = samec ? (sim - 1.0f) : sim;    // shared quadratic operand
            float t = fmaf(u * u, 256.0f, -16.0f);   // pos_q or neg_q pre-clamp
            if (!samec && sim < -0.25f) t = 0.0f;    // neg relu-clamp (exact)
            if (withDiag && n16 == quad * 4 + r) t = MASKP_;   // self-pair mask
            float ms = samec ? m_p[r] : m_n[r];
            if (t > ms) {                            // rare: running max moves
                float scl = __expf(ms - t);
                if (samec) { S_p[r] = fmaf(S_p[r], scl, 1.0f); m_p[r] = t; }
                else       { S_n[r] = fmaf(S_n[r], scl, 1.0f); m_n[r] = t; }
            } else {                                 // common: single exp
                float e = __expf(t - ms);
                S_p[r] += samec ? e : 0.0f;
                S_n[r] += samec ? 0.0f : e;
            }
            mxn[r] = fmaxf(mxn[r], samec ? -2.0f : sim);
        }
    };

    #pragma unroll 1
    for (int s = 0; s < NST; ++s) {
        const int b = s & 1;
        const int j0 = colBase + s * 16;
        __syncthreads();      // drains DMA for stage s (vmcnt) + all prior LDS reads

        if (s + 1 < NST) {    // one full stage of async overlap into the idle buffer
            const char* g2 = gstage + (size_t)(s + 1) * 16 * 1024;
            #pragma unroll
            for (int p = 0; p < 4; ++p) {
                int j = p * 4 + wave;
                __builtin_amdgcn_global_load_lds((gp_t)(const void*)(g2 + j * 1024),
                                                 (lp_t)(void*)&Bs[b ^ 1][j][0], 16, 0, 0);
            }
        }
        int tc_nxt = (s + 1 < NST) ? tg[colBase + (s + 1) * 16 + n16] : 0;

        f32x4 a0 = {0.f, 0.f, 0.f, 0.f}, a1 = {0.f, 0.f, 0.f, 0.f};
        #pragma unroll
        for (int kk = 0; kk < 8; ++kk) {
            bf16x8 bf0 = *(const bf16x8*)&Bs[b][n16][(2 * kk) * 32 + quad * 8];
            bf16x8 bf1 = *(const bf16x8*)&Bs[b][n16][(2 * kk + 1) * 32 + quad * 8];
            a0 = __builtin_amdgcn_mfma_f32_16x16x32_bf16(af[2 * kk],     bf0, a0, 0, 0, 0);
            a1 = __builtin_amdgcn_mfma_f32_16x16x32_bf16(af[2 * kk + 1], bf1, a1, 0, 0, 0);
        }

        // rows and stage-cols are both 16-aligned => diagonal only when j0==rowBase
        if (j0 == rowBase) epi(a0, a1, tc_cur, true);   // wave-uniform, 1 of 16 stages
        else               epi(a0, a1, tc_cur, false);
        tc_cur = tc_nxt;
    }

    // merge across the 16 lanes holding each row (waves own disjoint rows)
    #pragma unroll
    for (int r = 0; r < 4; ++r) {
        #pragma unroll
        for (int d = 1; d <= 8; d <<= 1) {
            lse_merge(__shfl_xor(m_p[r], d), __shfl_xor(S_p[r], d), m_p[r], S_p[r]);
            lse_merge(__shfl_xor(m_n[r], d), __shfl_xor(S_n[r], d), m_n[r], S_n[r]);
            mxn[r] = fmaxf(mxn[r], __shfl_xor(mxn[r], d));
        }
    }
    // packed partial (R8/R9-proven): pos side stores (max term, S) directly; neg
    // side stores (mxn, S) with implied m = max(0, neg_q(mxn)).
    if (n16 == 0) {
        #pragma unroll
        for (int r = 0; r < 4; ++r) {
            ((float4*)part)[(size_t)(rowBase + quad * 4 + r) * CCH_ + cc] =
                make_float4(m_p[r], S_p[r], mxn[r], S_n[r]);
        }
    }
}

// ---- reduce+final fused: hist, merge 16 chunks/row, hard-mining fix, softplus,
// ---- block atomics, then last-block ticket writes out = loss/valid ----
__global__ __launch_bounds__(256) void k_reduceF(const float* __restrict__ part,
                                                 const int* __restrict__ tg,
                                                 float* __restrict__ acc,
                                                 float* __restrict__ out) {
    __shared__ int hist[64];
    const int tid = threadIdx.x;
    if (tid < 64) hist[tid] = 0;
    __syncthreads();
    for (int i = tid; i < N_; i += 256) atomicAdd(&hist[tg[i]], 1);
    __syncthreads();

    const int row = blockIdx.x * 256 + tid;
    const float4* P = (const float4*)part + (size_t)row * CCH_;
    float M_p = MINITP_, Sp = 0.f, M_n = 0.f, Sn = 0.f, mxn = -2.0f;
    #pragma unroll
    for (int c = 0; c < CCH_; ++c) {
        float4 a = P[c];   // {m_p_c, Sp_c, mxn_c, Sn_c}
        lse_merge(a.x, a.y, M_p, Sp);
        float mn = (a.z > -1.5f) ? fmaxf(neg_q(a.z), 0.0f) : 0.0f;  // empty => no-op
        lse_merge(mn, a.w, M_n, Sn);
        mxn = fmaxf(mxn, a.z);
    }
    const int cnt = hist[tg[row]];
    float np2 = (float)(cnt - 1), nn2 = (float)(N_ - cnt);
    float loss = 0.f, vld = 0.f;
    if (np2 > 0.5f && nn2 > 0.5f) {
        if (np2 > 1.5f) {             // hard positive: its term (== M_p) doubles
            float t1 = M_p, t2 = 2.0f * t1;
            float mm = fmaxf(M_p, t2);
            Sp = Sp * __expf(M_p - mm) + __expf(t2 - mm) - __expf(t1 - mm);
            M_p = mm;
        }
        if (nn2 > 1.5f) {             // hard negative: term at max sim doubles
            float t1 = neg_q(mxn), t2 = 2.0f * t1;
            float mm = fmaxf(M_n, t2);
            Sn = Sn * __expf(M_n - mm) + __expf(t2 - mm) - __expf(t1 - mm);
            M_n = mm;
        }
        float z = (M_p + __logf(Sp)) + (M_n + __logf(Sn));
        loss = fmaxf(z, 0.0f) + log1pf(__expf(-fabsf(z)));   // softplus
        vld = 1.0f;
    }
    #pragma unroll
    for (int d = 32; d >= 1; d >>= 1) { loss += __shfl_xor(loss, d); vld += __shfl_xor(vld, d); }
    if ((tid & 63) == 0) { atomicAdd(&acc[0], loss); atomicAdd(&acc[1], vld); }

    __syncthreads();                  // this block's atomics are issued
    if (tid == 0) {
        __threadfence();              // device-scope: adds visible before ticket
        int old = atomicAdd((int*)(acc + 2), 1);            // acc[2] zeroed by k_norm
        if (old == (int)gridDim.x - 1) {                    // last block finalizes
            float ls = atomicAdd(&acc[0], 0.0f);            // device-scope reads
            float lv = atomicAdd(&acc[1], 0.0f);
            out[0] = ls / fmaxf(lv, 1.0f);
        }
    }
}

__global__ void k_final(const float* __restrict__ acc, float* __restrict__ out) {
    if (threadIdx.x == 0) out[0] = acc[0] / fmaxf(acc[1], 1.0f);
}

__global__ void k_sentinel(float* __restrict__ out) {
    if (threadIdx.x == 0) out[0] = -12345.0f;   // signals: ws too small
}

// ================= fallback path (round-4 exact, needs only 4MB+64) =================
__global__ __launch_bounds__(1024, 4) void k_main3(const unsigned short* __restrict__ xb,
                                                   const int* __restrict__ tg,
                                                   float* __restrict__ acc_g) {
    __shared__ __align__(16) unsigned short As[16 * AST_];
    __shared__ float sm[16][16][8];
    const int tid  = threadIdx.x;
    const int wave = tid >> 6, lane = tid & 63;
    const int n16  = lane & 15, quad = lane >> 4;
    const int rowBase = blockIdx.x * 16;
    {
        int row = tid >> 6, c = tid & 63;
        *(uint4*)&As[row * AST_ + c * 8] =
            *(const uint4*)(xb + (size_t)(rowBase + row) * D_ + c * 8);
    }
    int ir[4], tr[4];
    #pragma unroll
    for (int r = 0; r < 4; ++r) { ir[r] = rowBase + quad * 4 + r; tr[r] = tg[ir[r]]; }
    float m_p[4], S_p[4], m_n[4], S_n[4], mnp[4], mxn[4], sc[4];
    #pragma unroll
    for (int r = 0; r < 4; ++r) {
        m_p[r] = 0.f; S_p[r] = 0.f; m_n[r] = 0.f; S_n[r] = 0.f;
        mnp[r] = 2.0f; mxn[r] = -2.0f; sc[r] = 0.f;
    }
    __syncthreads();
    const unsigned short* Af = &As[n16 * AST_ + quad * 8];
    #pragma unroll 1
    for (int t = wave; t < N_ / 16; t += 16) {
        const int jcol = t * 16 + n16;
        const int tc = tg[jcol];
        const bf16x8* bp = (const bf16x8*)(xb + (size_t)jcol * D_ + quad * 8);
        bf16x8 bf[16];
        #pragma unroll
        for (int kk = 0; kk < 16; ++kk) bf[kk] = bp[kk * 4];
        f32x4 a0 = {0.f, 0.f, 0.f, 0.f}, a1 = {0.f, 0.f, 0.f, 0.f};
        #pragma unroll
        for (int kk = 0; kk < 8; ++kk) {
            bf16x8 af0 = *(const bf16x8*)(Af + (2 * kk) * 32);
            bf16x8 af1 = *(const bf16x8*)(Af + (2 * kk + 1) * 32);
            a0 = __builtin_amdgcn_mfma_f32_16x16x32_bf16(af0, bf[2 * kk],     a0, 0, 0, 0);
            a1 = __builtin_amdgcn_mfma_f32_16x16x32_bf16(af1, bf[2 * kk + 1], a1, 0, 0, 0);
        }
        #pragma unroll
        for (int r = 0; r < 4; ++r) {
            float s = a0[r] + a1[r];
            bool samec = (tr[r] == tc);
            bool posm  = samec && (jcol != ir[r]);
            float tp = posm  ? pos_q(s) : MASKT_;
            float tn = samec ? MASKT_ : neg_q(s);
            float mm = fmaxf(m_p[r], tp);
            S_p[r] = S_p[r] * __expf(m_p[r] - mm) + __expf(tp - mm); m_p[r] = mm;
            mm = fmaxf(m_n[r], tn);
            S_n[r] = S_n[r] * __expf(m_n[r] - mm) + __expf(tn - mm); m_n[r] = mm;
            sc[r] += samec ? 1.0f : 0.0f;
            mnp[r] = fminf(mnp[r], posm ? s : 2.0f);
            mxn[r] = fmaxf(mxn[r], samec ? -2.0f : s);
        }
    }
    #pragma unroll
    for (int r = 0; r < 4; ++r) {
        #pragma unroll
        for (int d = 1; d <= 8; d <<= 1) {
            lse_merge(__shfl_xor(m_p[r], d), __shfl_xor(S_p[r], d), m_p[r], S_p[r]);
            lse_merge(__shfl_xor(m_n[r], d), __shfl_xor(S_n[r], d), m_n[r], S_n[r]);
            mnp[r] = fminf(mnp[r], __shfl_xor(mnp[r], d));
            mxn[r] = fmaxf(mxn[r], __shfl_xor(mxn[r], d));
            sc[r] += __shfl_xor(sc[r], d);
        }
    }
    if (n16 == 0) {
        #pragma unroll
        for (int r = 0; r < 4; ++r) {
            float* q = sm[wave][quad * 4 + r];
            q[0] = m_p[r]; q[1] = S_p[r]; q[2] = m_n[r]; q[3] = S_n[r];
            q[4] = mnp[r]; q[5] = mxn[r]; q[6] = sc[r];
        }
    }
    __syncthreads();
    if (tid < 64) {
        const int L = tid & 15;
        float m_p2 = 0.f, S_p2 = 0.f, m_n2 = 0.f, S_n2 = 0.f;
        float mnp2 = 2.0f, mxn2 = -2.0f, sct = 0.f;
        #pragma unroll
        for (int w = 0; w < 16; ++w) {
            const float* q = sm[w][L];
            lse_merge(q[0], q[1], m_p2, S_p2);
            lse_merge(q[2], q[3], m_n2, S_n2);
            mnp2 = fminf(mnp2, q[4]); mxn2 = fmaxf(mxn2, q[5]);
            sct += q[6];
        }
        float loss = 0.f, vld = 0.f;
        float np2 = sct - 1.0f, nn2 = (float)N_ - sct;
        if (tid < 16 && np2 > 0.5f && nn2 > 0.5f) {
            if (np2 > 1.5f) {
                float t1 = pos_q(mnp2), t2 = 2.0f * t1;
                float mm = fmaxf(m_p2, t2);
                S_p2 = S_p2 * __expf(m_p2 - mm) + __expf(t2 - mm) - __expf(t1 - mm);
                m_p2 = mm;
            }
            if (nn2 > 1.5f) {
                float t1 = neg_q(mxn2), t2 = 2.0f * t1;
                float mm = fmaxf(m_n2, t2);
                S_n2 = S_n2 * __expf(m_n2 - mm) + __expf(t2 - mm) - __expf(t1 - mm);
                m_n2 = mm;
            }
            float z = (m_p2 + __logf(S_p2)) + (m_n2 + __logf(S_n2));
            loss = fmaxf(z, 0.0f) + log1pf(__expf(-fabsf(z)));
            vld = 1.0f;
        }
        #pragma unroll
        for (int d = 32; d >= 1; d >>= 1) {
            loss += __shfl_xor(loss, d); vld += __shfl_xor(vld, d);
        }
        if (tid == 0) { atomicAdd(&acc_g[0], loss); atomicAdd(&acc_g[1], vld); }
    }
}

extern "C" void kernel_launch(void* const* d_in, const int* in_sizes, int n_in,
                              void* d_out, int out_size, void* d_ws, size_t ws_size,
                              hipStream_t stream) {
    const float* in = (const float*)d_in[0];
    const int*   tg = (const int*)d_in[1];
    constexpr size_t MB = 1024 * 1024;
    unsigned short* xb = (unsigned short*)d_ws;

    if (ws_size >= 5 * MB + 64) {
        float* part = (float*)((char*)d_ws + 4 * MB);
        float* acc  = (float*)((char*)d_ws + 5 * MB);
        hipLaunchKernelGGL(k_norm,    dim3(N_ / 4),    dim3(256), 0, stream, in, xb, acc);
        hipLaunchKernelGGL(k_mainG,   dim3(64 * CCH_), dim3(256), 0, stream, xb, tg, part);
        hipLaunchKernelGGL(k_reduceF, dim3(N_ / 256),  dim3(256), 0, stream, part, tg, acc,
                           (float*)d_out);
    } else if (ws_size >= 4 * MB + 64) {
        float* acc = (float*)((char*)d_ws + 4 * MB);
        hipLaunchKernelGGL(k_norm,  dim3(N_ / 4),  dim3(256),  0, stream, in, xb, acc);
        hipLaunchKernelGGL(k_main3, dim3(N_ / 16), dim3(1024), 0, stream, xb, tg, acc);
        hipLaunchKernelGGL(k_final, dim3(1),       dim3(64),   0, stream, acc, (float*)d_out);
    } else {
        hipLaunchKernelGGL(k_sentinel, dim3(1), dim3(64), 0, stream, (float*)d_out);
    }
}